// Round 1
// baseline (847.547 us; speedup 1.0000x reference)
//
#include <hip/hip_runtime.h>

#define N_   8
#define T_   300
#define U_   60
#define U1_  61
#define EENC 320
#define NHID 512
#define VOC  128

__device__ __forceinline__ float fast_tanh(float x) {
    x = fminf(fmaxf(x, -15.f), 15.f);
    float e = __expf(2.f * x);
    return __fdividef(e - 1.f, e + 1.f);
}

// Y[R,512] = X[R,320] @ W[320,512] (+bias)
__global__ __launch_bounds__(512) void proj_kernel(
    const float* __restrict__ X, const float* __restrict__ W,
    const float* __restrict__ bias, float* __restrict__ Y, int R)
{
    __shared__ float xs[16][EENC];
    const int tid  = threadIdx.x;
    const int row0 = blockIdx.x * 16;
    for (int i = tid; i < 16 * EENC; i += 512) {
        int r = i / EENC, e = i - r * EENC;
        float v = 0.f;
        if (row0 + r < R) v = X[(row0 + r) * EENC + e];
        xs[r][e] = v;
    }
    __syncthreads();
    float acc[16];
    #pragma unroll
    for (int r = 0; r < 16; ++r) acc[r] = 0.f;
    const int h = tid;
    for (int e = 0; e < EENC; e += 4) {
        float w0 = W[(e + 0) * NHID + h];
        float w1 = W[(e + 1) * NHID + h];
        float w2 = W[(e + 2) * NHID + h];
        float w3 = W[(e + 3) * NHID + h];
        #pragma unroll
        for (int r = 0; r < 16; ++r) {
            float4 xv = *(const float4*)&xs[r][e];
            acc[r] = fmaf(xv.x, w0, fmaf(xv.y, w1, fmaf(xv.z, w2, fmaf(xv.w, w3, acc[r]))));
        }
    }
    float b = bias ? bias[h] : 0.f;
    #pragma unroll
    for (int r = 0; r < 16; ++r)
        if (row0 + r < R) Y[(row0 + r) * NHID + h] = acc[r] + b;
}

// One block per (n, t, u-half). 32 cells x 128 vocab.
// Computes blank_lp[n,t,u] and emit_lp[n,t,u] without materializing logits.
__global__ __launch_bounds__(256) void joint_kernel(
    const float* __restrict__ encp,    // [N*T, 512]
    const float* __restrict__ decp,    // [N*U1, 512] (b_joint folded in)
    const float* __restrict__ Wo,      // [512, 128]
    const float* __restrict__ bo,      // [128]
    const int*   __restrict__ targets, // [N, U]
    float* __restrict__ blankp,        // [N*T, 61]
    float* __restrict__ emitp)         // [N*T, 60]
{
    __shared__ float th[NHID][32];     // [k][m], 64 KB
    const int tid  = threadIdx.x;
    const int bid  = blockIdx.x;
    const int half = bid & 1;
    const int nt   = bid >> 1;
    const int n    = nt / T_;
    const int u0   = half * 32;

    // ---- phase 1: th[k][m] = tanh(encp[nt,k] + decp[n,u0+m,k]) ----
    {
        const int m0 = (tid & 7) * 4;
        const int kb = tid >> 3;       // 0..31
        int ur[4];
        #pragma unroll
        for (int mi = 0; mi < 4; ++mi) ur[mi] = min(u0 + m0 + mi, U_); // clamp (garbage cells never stored)
        const float* er = encp + nt * NHID;
        const float* d0 = decp + (n * U1_ + ur[0]) * NHID;
        const float* d1 = decp + (n * U1_ + ur[1]) * NHID;
        const float* d2 = decp + (n * U1_ + ur[2]) * NHID;
        const float* d3 = decp + (n * U1_ + ur[3]) * NHID;
        #pragma unroll 4
        for (int ki = 0; ki < 16; ++ki) {
            int k = kb + ki * 32;
            float ev = er[k];
            float4 r;
            r.x = fast_tanh(ev + d0[k]);
            r.y = fast_tanh(ev + d1[k]);
            r.z = fast_tanh(ev + d2[k]);
            r.w = fast_tanh(ev + d3[k]);
            *(float4*)&th[k][m0] = r;
        }
    }
    __syncthreads();

    // ---- phase 2: logits tile [32 cells][128 vocab], outer-product ----
    const int vg  = tid & 31;          // vocab group: v = vg*4 .. vg*4+3
    const int mg4 = (tid >> 5) * 4;    // cell group:  m = mg4 .. mg4+3
    float acc[4][4];
    #pragma unroll
    for (int i = 0; i < 4; ++i)
        #pragma unroll
        for (int j = 0; j < 4; ++j) acc[i][j] = 0.f;

    const float4* Wo4 = (const float4*)Wo;
    #pragma unroll 4
    for (int k = 0; k < NHID; ++k) {
        float4 w = Wo4[k * 32 + vg];
        float t0 = th[k][mg4 + 0];
        float t1 = th[k][mg4 + 1];
        float t2 = th[k][mg4 + 2];
        float t3 = th[k][mg4 + 3];
        acc[0][0] = fmaf(t0, w.x, acc[0][0]); acc[0][1] = fmaf(t0, w.y, acc[0][1]);
        acc[0][2] = fmaf(t0, w.z, acc[0][2]); acc[0][3] = fmaf(t0, w.w, acc[0][3]);
        acc[1][0] = fmaf(t1, w.x, acc[1][0]); acc[1][1] = fmaf(t1, w.y, acc[1][1]);
        acc[1][2] = fmaf(t1, w.z, acc[1][2]); acc[1][3] = fmaf(t1, w.w, acc[1][3]);
        acc[2][0] = fmaf(t2, w.x, acc[2][0]); acc[2][1] = fmaf(t2, w.y, acc[2][1]);
        acc[2][2] = fmaf(t2, w.z, acc[2][2]); acc[2][3] = fmaf(t2, w.w, acc[2][3]);
        acc[3][0] = fmaf(t3, w.x, acc[3][0]); acc[3][1] = fmaf(t3, w.y, acc[3][1]);
        acc[3][2] = fmaf(t3, w.z, acc[3][2]); acc[3][3] = fmaf(t3, w.w, acc[3][3]);
    }

    float4 bov = *(const float4*)&bo[vg * 4];
    #pragma unroll
    for (int i = 0; i < 4; ++i) {
        float l0 = acc[i][0] + bov.x, l1 = acc[i][1] + bov.y;
        float l2 = acc[i][2] + bov.z, l3 = acc[i][3] + bov.w;
        float mx = fmaxf(fmaxf(l0, l1), fmaxf(l2, l3));
        #pragma unroll
        for (int off = 16; off >= 1; off >>= 1) mx = fmaxf(mx, __shfl_xor(mx, off));
        float s = __expf(l0 - mx) + __expf(l1 - mx) + __expf(l2 - mx) + __expf(l3 - mx);
        #pragma unroll
        for (int off = 16; off >= 1; off >>= 1) s += __shfl_xor(s, off);
        float lse = mx + __logf(s);
        int u = u0 + mg4 + i;
        if (u < U1_ && vg == 0) blankp[nt * U1_ + u] = l0 - lse;  // v=0 is BLANK
        if (u < U_) {
            int lab = targets[n * U_ + u];
            if ((lab >> 2) == vg) {
                int jj = lab & 3;
                float lv = jj == 0 ? l0 : (jj == 1 ? l1 : (jj == 2 ? l2 : l3));
                emitp[nt * U_ + u] = lv - lse;
            }
        }
    }
}

// Anti-diagonal wavefront DP. One wave per batch (8 waves, 1 block).
// lane u holds alpha[t][u] for t = d-u on diagonal d.
__global__ __launch_bounds__(512) void dp_kernel(
    const float* __restrict__ blankp, const float* __restrict__ emitp,
    const int* __restrict__ inputs_len, const int* __restrict__ targets_len,
    float* __restrict__ out)
{
    __shared__ float losses[N_];
    const int n = threadIdx.x >> 6;
    const int u = threadIdx.x & 63;
    const float* B = blankp + n * T_ * U1_;
    const float* E = emitp + n * T_ * U_;
    const int ti = inputs_len[n] - 1;
    const int ui = targets_len[n];
    const float NEG = -1e30f;
    float a = (u == 0) ? 0.f : NEG;

    const int uB = min(u, U_);                  // clamped load addresses (inactive lanes)
    const int uE = min(max(u - 1, 0), U_ - 1);
    const int PF = 8;
    float bl[PF], em[PF];
    #pragma unroll
    for (int j = 0; j < PF; ++j) {
        int d = 1 + j;
        int t = d - u;
        bl[j] = B[min(max(t - 1, 0), T_ - 1) * U1_ + uB];
        em[j] = E[min(max(t, 0), T_ - 1) * U_ + uE];
    }

    const int DMAX = T_ + U_;                   // 360
    for (int d0 = 1; d0 <= DMAX; d0 += PF) {
        #pragma unroll
        for (int j = 0; j < PF; ++j) {
            int d = d0 + j;
            float av = __shfl_up(a, 1);         // alpha[t][u-1] from lane u-1
            float b_ = bl[j], e_ = em[j];
            // prefetch depth-PF ahead (addresses are DP-independent)
            int tn = d + PF - u;
            bl[j] = B[min(max(tn - 1, 0), T_ - 1) * U1_ + uB];
            em[j] = E[min(max(tn, 0), T_ - 1) * U_ + uE];
            int t = d - u;
            if (t >= 0 && t < T_ && u < U1_) {
                float anew;
                if (t == 0)      anew = av + e_;        // cumsum row
                else if (u == 0) anew = a + b_;         // blank-only column
                else {
                    float x = a + b_;                   // from (t-1,u) via blank
                    float y = av + e_;                  // from (t,u-1) via emit
                    float mx = fmaxf(x, y);
                    float mn = fminf(x, y);
                    anew = mx + __logf(1.f + __expf(mn - mx));
                }
                a = anew;
                if (t == ti && u == ui) losses[n] = -(anew + B[t * U1_ + u]);
            }
        }
    }
    __syncthreads();
    if (threadIdx.x == 0) {
        float s = 0.f;
        #pragma unroll
        for (int i = 0; i < N_; ++i) s += losses[i];
        out[0] = s * (1.0f / N_);
    }
}

extern "C" void kernel_launch(void* const* d_in, const int* in_sizes, int n_in,
                              void* d_out, int out_size, void* d_ws, size_t ws_size,
                              hipStream_t stream)
{
    const float* enc         = (const float*)d_in[0];
    const float* dec         = (const float*)d_in[1];
    const int*   targets     = (const int*)d_in[2];
    const int*   inputs_len  = (const int*)d_in[3];
    const int*   targets_len = (const int*)d_in[4];
    const float* Wj          = (const float*)d_in[5];
    const float* bj          = (const float*)d_in[6];
    const float* Wo          = (const float*)d_in[7];
    const float* bo          = (const float*)d_in[8];
    float* out = (float*)d_out;

    char* ws = (char*)d_ws;
    float* encp   = (float*)ws;                                   // 2400*512 f32
    float* decp   = (float*)(ws + (size_t)2400 * 512 * 4);        // 488*512 f32
    float* blankp = (float*)(ws + (size_t)(2400 + 488) * 512 * 4);// 8*300*61 f32
    float* emitp  = blankp + N_ * T_ * U1_;                       // 8*300*60 f32

    proj_kernel<<<150, 512, 0, stream>>>(enc, Wj, nullptr, encp, N_ * T_);
    proj_kernel<<<31, 512, 0, stream>>>(dec, Wj + EENC * NHID, bj, decp, N_ * U1_);
    joint_kernel<<<N_ * T_ * 2, 256, 0, stream>>>(encp, decp, Wo, bo, targets, blankp, emitp);
    dp_kernel<<<1, 512, 0, stream>>>(blankp, emitp, inputs_len, targets_len, out);
}

// Round 2
// 523.510 us; speedup vs baseline: 1.6190x; 1.6190x over previous
//
#include <hip/hip_runtime.h>
#include <hip/hip_bf16.h>

#define N_   8
#define T_   300
#define U_   60
#define U1_  61
#define EENC 320
#define NHID 512
#define VOC  128

typedef __attribute__((ext_vector_type(8))) short bf16x8;
typedef __attribute__((ext_vector_type(4))) float f32x4;

__device__ __forceinline__ unsigned short f2bf(float f) {
    unsigned int u = __float_as_uint(f);
    u += 0x7fff + ((u >> 16) & 1);          // RNE
    return (unsigned short)(u >> 16);
}

__device__ __forceinline__ float fast_tanh(float x) {
    x = fminf(fmaxf(x, -10.f), 10.f);
    float e = __expf(2.f * x);
    return 1.f - __fdividef(2.f, e + 1.f);
}

// ---- pre-pass: fp32 -> bf16 copy-convert (enc, dec) ----
__global__ __launch_bounds__(256) void convert_copy(
    const float* __restrict__ enc, const float* __restrict__ dec,
    unsigned short* __restrict__ encB, unsigned short* __restrict__ decB)
{
    const int NE4 = (N_ * T_ * EENC) / 4;        // 192000
    const int ND4 = (N_ * U1_ * EENC) / 4;       // 39040
    int idx = blockIdx.x * 256 + threadIdx.x;
    if (idx >= NE4 + ND4) return;
    const float4* src; ushort4* dst; int i;
    if (idx < NE4) { src = (const float4*)enc; dst = (ushort4*)encB; i = idx; }
    else           { src = (const float4*)dec; dst = (ushort4*)decB; i = idx - NE4; }
    float4 v = src[i];
    ushort4 o;
    o.x = f2bf(v.x); o.y = f2bf(v.y); o.z = f2bf(v.z); o.w = f2bf(v.w);
    dst[i] = o;
}

// ---- pre-pass: transpose-convert Wj [320,512]->WjT [512][320], Wo [512,128]->WoT [128][512] ----
__global__ __launch_bounds__(256) void convert_tr(
    const float* __restrict__ Wj, const float* __restrict__ Wo,
    unsigned short* __restrict__ WjT, unsigned short* __restrict__ WoT)
{
    int i = blockIdx.x * 256 + threadIdx.x;
    const int NJ = NHID * EENC;                  // 163840
    if (i < NJ) {
        int c = i / EENC, k = i - c * EENC;
        WjT[i] = f2bf(Wj[k * NHID + c]);
    } else {
        int j = i - NJ;
        if (j < VOC * NHID) {
            int v = j >> 9, k = j & 511;
            WoT[j] = f2bf(Wo[k * VOC + v]);
        }
    }
}

// ---- projection GEMM: C[R,512] = A[R,320](bf16) @ WjT^T, optional bias ----
// block: 128 rows x 128 cols; 4 waves in 2x2; 16x16x32 bf16 MFMA
__global__ __launch_bounds__(256) void proj_mfma(
    const unsigned short* __restrict__ A,   // [R][320] bf16
    const unsigned short* __restrict__ BT,  // [512][320] bf16
    const float* __restrict__ bias,         // [512] or null
    float* __restrict__ C, int R)
{
    __shared__ short lA[128 * 64];
    __shared__ short lB[128 * 64];
    const int tid = threadIdx.x, lane = tid & 63, wave = tid >> 6;
    const int rb = blockIdx.x >> 2, cb = blockIdx.x & 3;
    const int rh = wave & 1, ch = wave >> 1;
    const int srow = (tid >> 3) & 31, sg = tid & 7;
    const int frow = lane & 15, fg = lane >> 4, quad = lane >> 4;

    f32x4 acc[4][4];
    f32x4 z = {0.f, 0.f, 0.f, 0.f};
    #pragma unroll
    for (int a = 0; a < 4; ++a)
        #pragma unroll
        for (int b = 0; b < 4; ++b) acc[a][b] = z;

    for (int s = 0; s < 5; ++s) {            // K=320, slices of 64
        __syncthreads();
        #pragma unroll
        for (int it = 0; it < 4; ++it) {
            int row = srow + it * 32;
            int grow = rb * 128 + row; if (grow >= R) grow = R - 1;
            bf16x8 va = *(const bf16x8*)(A + grow * EENC + s * 64 + sg * 8);
            *(bf16x8*)&lA[row * 64 + ((sg ^ (row & 7)) << 3)] = va;
            int col = row;
            bf16x8 vb = *(const bf16x8*)(BT + (cb * 128 + col) * EENC + s * 64 + sg * 8);
            *(bf16x8*)&lB[col * 64 + ((sg ^ (col & 7)) << 3)] = vb;
        }
        __syncthreads();
        #pragma unroll
        for (int ks = 0; ks < 2; ++ks) {
            int g = fg + ks * 4;
            bf16x8 af[4], bf[4];
            #pragma unroll
            for (int rt = 0; rt < 4; ++rt) {
                int row = rh * 64 + rt * 16 + frow;
                af[rt] = *(const bf16x8*)&lA[row * 64 + ((g ^ (row & 7)) << 3)];
            }
            #pragma unroll
            for (int c = 0; c < 4; ++c) {
                int col = ch * 64 + c * 16 + frow;
                bf[c] = *(const bf16x8*)&lB[col * 64 + ((g ^ (col & 7)) << 3)];
            }
            #pragma unroll
            for (int rt = 0; rt < 4; ++rt)
                #pragma unroll
                for (int c = 0; c < 4; ++c)
                    acc[rt][c] = __builtin_amdgcn_mfma_f32_16x16x32_bf16(af[rt], bf[c], acc[rt][c], 0, 0, 0);
        }
    }
    #pragma unroll
    for (int rt = 0; rt < 4; ++rt) {
        int grow0 = rb * 128 + rh * 64 + rt * 16 + quad * 4;
        #pragma unroll
        for (int c = 0; c < 4; ++c) {
            int col = cb * 128 + ch * 64 + c * 16 + frow;
            float b = bias ? bias[col] : 0.f;
            #pragma unroll
            for (int r = 0; r < 4; ++r) {
                int gr = grow0 + r;
                if (gr < R) C[gr * NHID + col] = acc[rt][c][r] + b;
            }
        }
    }
}

// ---- joint: per block 2 nt x 64 u(padded) x 128 vocab; fused tanh + GEMM + LSE ----
__global__ __launch_bounds__(256) void joint_mfma(
    const float* __restrict__ encp,          // [2400][512]
    const float* __restrict__ decp,          // [488][512] (b_joint folded)
    const unsigned short* __restrict__ WoT,  // [128][512] bf16
    const float* __restrict__ bo,            // [128]
    const int* __restrict__ targets,         // [8][60]
    float* __restrict__ blankp, float* __restrict__ emitp)
{
    __shared__ short lA[128 * 64];
    __shared__ short lB[128 * 64];
    __shared__ float bo_s[VOC];
    __shared__ int   lab_s[U_];
    __shared__ float red_m[2][128];
    __shared__ float red_s[2][128];

    const int tid = threadIdx.x, lane = tid & 63, wave = tid >> 6;
    const int nt0 = 2 * blockIdx.x, n = nt0 / T_;
    if (tid < VOC) bo_s[tid] = bo[tid];
    if (tid >= 128 && tid < 128 + U_) lab_s[tid - 128] = targets[n * U_ + (tid - 128)];

    const int rh = wave & 1, ch = wave >> 1;
    const int srow = (tid >> 3) & 31, sg = tid & 7;
    const int frow = lane & 15, fg = lane >> 4, quad = lane >> 4;

    f32x4 acc[4][4];
    f32x4 z = {0.f, 0.f, 0.f, 0.f};
    #pragma unroll
    for (int a = 0; a < 4; ++a)
        #pragma unroll
        for (int b = 0; b < 4; ++b) acc[a][b] = z;

    for (int s = 0; s < 8; ++s) {            // K=512, slices of 64
        __syncthreads();
        #pragma unroll
        for (int it = 0; it < 4; ++it) {
            int row = srow + it * 32;
            int u = row & 63; if (u > U_) u = U_;
            int nt = nt0 + (row >> 6);
            const float* ep = encp + nt * NHID + s * 64 + sg * 8;
            const float* dp = decp + (n * U1_ + u) * NHID + s * 64 + sg * 8;
            float4 e0 = *(const float4*)ep, e1 = *(const float4*)(ep + 4);
            float4 d0 = *(const float4*)dp, d1 = *(const float4*)(dp + 4);
            bf16x8 va;
            va[0] = (short)f2bf(fast_tanh(e0.x + d0.x));
            va[1] = (short)f2bf(fast_tanh(e0.y + d0.y));
            va[2] = (short)f2bf(fast_tanh(e0.z + d0.z));
            va[3] = (short)f2bf(fast_tanh(e0.w + d0.w));
            va[4] = (short)f2bf(fast_tanh(e1.x + d1.x));
            va[5] = (short)f2bf(fast_tanh(e1.y + d1.y));
            va[6] = (short)f2bf(fast_tanh(e1.z + d1.z));
            va[7] = (short)f2bf(fast_tanh(e1.w + d1.w));
            *(bf16x8*)&lA[row * 64 + ((sg ^ (row & 7)) << 3)] = va;
            int col = row;
            bf16x8 vb = *(const bf16x8*)(WoT + col * NHID + s * 64 + sg * 8);
            *(bf16x8*)&lB[col * 64 + ((sg ^ (col & 7)) << 3)] = vb;
        }
        __syncthreads();
        #pragma unroll
        for (int ks = 0; ks < 2; ++ks) {
            int g = fg + ks * 4;
            bf16x8 af[4], bf[4];
            #pragma unroll
            for (int rt = 0; rt < 4; ++rt) {
                int row = rh * 64 + rt * 16 + frow;
                af[rt] = *(const bf16x8*)&lA[row * 64 + ((g ^ (row & 7)) << 3)];
            }
            #pragma unroll
            for (int c = 0; c < 4; ++c) {
                int col = ch * 64 + c * 16 + frow;
                bf[c] = *(const bf16x8*)&lB[col * 64 + ((g ^ (col & 7)) << 3)];
            }
            #pragma unroll
            for (int rt = 0; rt < 4; ++rt)
                #pragma unroll
                for (int c = 0; c < 4; ++c)
                    acc[rt][c] = __builtin_amdgcn_mfma_f32_16x16x32_bf16(af[rt], bf[c], acc[rt][c], 0, 0, 0);
        }
    }

    // ---- epilogue: bias, per-row LSE over 128 cols, store blank/target ----
    #pragma unroll
    for (int rt = 0; rt < 4; ++rt)
        #pragma unroll
        for (int c = 0; c < 4; ++c) {
            float b = bo_s[ch * 64 + c * 16 + frow];
            #pragma unroll
            for (int r = 0; r < 4; ++r) acc[rt][c][r] += b;
        }

    float m_l[4][4], s_l[4][4];
    #pragma unroll
    for (int rt = 0; rt < 4; ++rt)
        #pragma unroll
        for (int r = 0; r < 4; ++r) {
            float m = -1e30f;
            #pragma unroll
            for (int c = 0; c < 4; ++c) m = fmaxf(m, acc[rt][c][r]);
            m_l[rt][r] = m;
        }
    #pragma unroll
    for (int off = 1; off < 16; off <<= 1)
        #pragma unroll
        for (int rt = 0; rt < 4; ++rt)
            #pragma unroll
            for (int r = 0; r < 4; ++r)
                m_l[rt][r] = fmaxf(m_l[rt][r], __shfl_xor(m_l[rt][r], off));
    #pragma unroll
    for (int rt = 0; rt < 4; ++rt)
        #pragma unroll
        for (int r = 0; r < 4; ++r) {
            float s = 0.f;
            #pragma unroll
            for (int c = 0; c < 4; ++c) s += __expf(acc[rt][c][r] - m_l[rt][r]);
            s_l[rt][r] = s;
        }
    #pragma unroll
    for (int off = 1; off < 16; off <<= 1)
        #pragma unroll
        for (int rt = 0; rt < 4; ++rt)
            #pragma unroll
            for (int r = 0; r < 4; ++r)
                s_l[rt][r] += __shfl_xor(s_l[rt][r], off);

    if (frow == 0) {
        #pragma unroll
        for (int rt = 0; rt < 4; ++rt)
            #pragma unroll
            for (int r = 0; r < 4; ++r) {
                int row = rh * 64 + rt * 16 + quad * 4 + r;
                red_m[ch][row] = m_l[rt][r];
                red_s[ch][row] = s_l[rt][r];
            }
    }
    __syncthreads();

    #pragma unroll
    for (int rt = 0; rt < 4; ++rt)
        #pragma unroll
        for (int r = 0; r < 4; ++r) {
            int row = rh * 64 + rt * 16 + quad * 4 + r;
            float m0 = red_m[0][row], m1 = red_m[1][row];
            float s0 = red_s[0][row], s1 = red_s[1][row];
            float M = fmaxf(m0, m1);
            float lse = M + __logf(s0 * __expf(m0 - M) + s1 * __expf(m1 - M));
            int u = row & 63;
            int nt = nt0 + (row >> 6);
            #pragma unroll
            for (int c = 0; c < 4; ++c) {
                int col = ch * 64 + c * 16 + frow;
                float val = acc[rt][c][r] - lse;
                if (col == 0 && u < U1_) blankp[nt * U1_ + u] = val;
                if (u < U_ && col == lab_s[u]) emitp[nt * U_ + u] = val;
            }
        }
}

// ---- anti-diagonal wavefront DP (unchanged from R1, passed) ----
__global__ __launch_bounds__(512) void dp_kernel(
    const float* __restrict__ blankp, const float* __restrict__ emitp,
    const int* __restrict__ inputs_len, const int* __restrict__ targets_len,
    float* __restrict__ out)
{
    __shared__ float losses[N_];
    const int n = threadIdx.x >> 6;
    const int u = threadIdx.x & 63;
    const float* B = blankp + n * T_ * U1_;
    const float* E = emitp + n * T_ * U_;
    const int ti = inputs_len[n] - 1;
    const int ui = targets_len[n];
    const float NEG = -1e30f;
    float a = (u == 0) ? 0.f : NEG;

    const int uB = min(u, U_);
    const int uE = min(max(u - 1, 0), U_ - 1);
    const int PF = 8;
    float bl[PF], em[PF];
    #pragma unroll
    for (int j = 0; j < PF; ++j) {
        int d = 1 + j;
        int t = d - u;
        bl[j] = B[min(max(t - 1, 0), T_ - 1) * U1_ + uB];
        em[j] = E[min(max(t, 0), T_ - 1) * U_ + uE];
    }
    const int DMAX = T_ + U_;
    for (int d0 = 1; d0 <= DMAX; d0 += PF) {
        #pragma unroll
        for (int j = 0; j < PF; ++j) {
            int d = d0 + j;
            float av = __shfl_up(a, 1);
            float b_ = bl[j], e_ = em[j];
            int tn = d + PF - u;
            bl[j] = B[min(max(tn - 1, 0), T_ - 1) * U1_ + uB];
            em[j] = E[min(max(tn, 0), T_ - 1) * U_ + uE];
            int t = d - u;
            if (t >= 0 && t < T_ && u < U1_) {
                float anew;
                if (t == 0)      anew = av + e_;
                else if (u == 0) anew = a + b_;
                else {
                    float x = a + b_;
                    float y = av + e_;
                    float mx = fmaxf(x, y);
                    float mn = fminf(x, y);
                    anew = mx + __logf(1.f + __expf(mn - mx));
                }
                a = anew;
                if (t == ti && u == ui) losses[n] = -(anew + B[t * U1_ + u]);
            }
        }
    }
    __syncthreads();
    if (threadIdx.x == 0) {
        float s = 0.f;
        #pragma unroll
        for (int i = 0; i < N_; ++i) s += losses[i];
        out[0] = s * (1.0f / N_);
    }
}

extern "C" void kernel_launch(void* const* d_in, const int* in_sizes, int n_in,
                              void* d_out, int out_size, void* d_ws, size_t ws_size,
                              hipStream_t stream)
{
    const float* enc         = (const float*)d_in[0];
    const float* dec         = (const float*)d_in[1];
    const int*   targets     = (const int*)d_in[2];
    const int*   inputs_len  = (const int*)d_in[3];
    const int*   targets_len = (const int*)d_in[4];
    const float* Wj          = (const float*)d_in[5];
    const float* bj          = (const float*)d_in[6];
    const float* Wo          = (const float*)d_in[7];
    const float* bo          = (const float*)d_in[8];
    float* out = (float*)d_out;

    char* ws = (char*)d_ws;
    float*          encp   = (float*)(ws + 0);                      // 2400*512 f32
    float*          decp   = (float*)(ws + 4915200);                // 488*512 f32
    float*          blankp = (float*)(ws + 5914624);                // 8*300*61 f32
    float*          emitp  = (float*)(ws + 6500224);                // 8*300*60 f32
    unsigned short* encB   = (unsigned short*)(ws + 7076224);       // 2400*320 bf16
    unsigned short* decB   = (unsigned short*)(ws + 8612224);       // 488*320 bf16
    unsigned short* WjT    = (unsigned short*)(ws + 8924544);       // 512*320 bf16
    unsigned short* WoT    = (unsigned short*)(ws + 9252224);       // 128*512 bf16

    convert_copy<<<903, 256, 0, stream>>>(enc, dec, encB, decB);
    convert_tr<<<896, 256, 0, stream>>>(Wj, Wo, WjT, WoT);
    proj_mfma<<<19 * 4, 256, 0, stream>>>(encB, WjT, nullptr, encp, N_ * T_);
    proj_mfma<<<4 * 4, 256, 0, stream>>>(decB, WjT, bj, decp, N_ * U1_);
    joint_mfma<<<1200, 256, 0, stream>>>(encp, decp, WoT, bo, targets, blankp, emitp);
    dp_kernel<<<1, 512, 0, stream>>>(blankp, emitp, inputs_len, targets_len, out);
}

// Round 3
// 327.406 us; speedup vs baseline: 2.5887x; 1.5990x over previous
//
#include <hip/hip_runtime.h>
#include <hip/hip_bf16.h>

#define N_   8
#define T_   300
#define U_   60
#define U1_  61
#define EENC 320
#define NHID 512
#define VOC  128

typedef __attribute__((ext_vector_type(8))) short bf16x8;
typedef __attribute__((ext_vector_type(4))) float f32x4;

__device__ __forceinline__ unsigned short f2bf(float f) {
    unsigned int u = __float_as_uint(f);
    u += 0x7fff + ((u >> 16) & 1);          // RNE
    return (unsigned short)(u >> 16);
}

__device__ __forceinline__ float fast_tanh(float x) {
    x = fminf(fmaxf(x, -10.f), 10.f);
    float e = __expf(2.f * x);
    return 1.f - __fdividef(2.f, e + 1.f);
}

// ---- merged pre-pass: bf16 copy-convert (enc,dec) + transpose-convert (Wj,Wo) ----
__global__ __launch_bounds__(256) void convert_all(
    const float* __restrict__ enc, const float* __restrict__ dec,
    const float* __restrict__ Wj, const float* __restrict__ Wo,
    unsigned short* __restrict__ encB, unsigned short* __restrict__ decB,
    unsigned short* __restrict__ WjT, unsigned short* __restrict__ WoT)
{
    const int bid = blockIdx.x;
    if (bid < 903) {                             // float4 copy-convert path
        const int NE4 = (N_ * T_ * EENC) / 4;    // 192000
        const int ND4 = (N_ * U1_ * EENC) / 4;   // 39040
        int idx = bid * 256 + threadIdx.x;
        if (idx >= NE4 + ND4) return;
        const float4* src; ushort4* dst; int i;
        if (idx < NE4) { src = (const float4*)enc; dst = (ushort4*)encB; i = idx; }
        else           { src = (const float4*)dec; dst = (ushort4*)decB; i = idx - NE4; }
        float4 v = src[i];
        ushort4 o;
        o.x = f2bf(v.x); o.y = f2bf(v.y); o.z = f2bf(v.z); o.w = f2bf(v.w);
        dst[i] = o;
    } else {                                     // transpose-convert path
        int i = (bid - 903) * 256 + threadIdx.x;
        const int NJ = NHID * EENC;              // 163840
        if (i < NJ) {
            int c = i / EENC, k = i - c * EENC;
            WjT[i] = f2bf(Wj[k * NHID + c]);
        } else {
            int j = i - NJ;
            if (j < VOC * NHID) {
                int v = j >> 9, k = j & 511;
                WoT[j] = f2bf(Wo[k * VOC + v]);
            }
        }
    }
}

// ---- projection GEMM: C[R,512] = A[R,320](bf16) @ WjT^T, optional bias ----
__global__ __launch_bounds__(256) void proj_mfma(
    const unsigned short* __restrict__ A,   // [R][320] bf16
    const unsigned short* __restrict__ BT,  // [512][320] bf16
    const float* __restrict__ bias,         // [512] or null
    float* __restrict__ C, int R)
{
    __shared__ short lA[128 * 64];
    __shared__ short lB[128 * 64];
    const int tid = threadIdx.x, lane = tid & 63, wave = tid >> 6;
    const int rb = blockIdx.x >> 2, cb = blockIdx.x & 3;
    const int rh = wave & 1, ch = wave >> 1;
    const int srow = (tid >> 3) & 31, sg = tid & 7;
    const int frow = lane & 15, fg = lane >> 4, quad = lane >> 4;

    f32x4 acc[4][4];
    f32x4 z = {0.f, 0.f, 0.f, 0.f};
    #pragma unroll
    for (int a = 0; a < 4; ++a)
        #pragma unroll
        for (int b = 0; b < 4; ++b) acc[a][b] = z;

    for (int s = 0; s < 5; ++s) {            // K=320, slices of 64
        __syncthreads();
        #pragma unroll
        for (int it = 0; it < 4; ++it) {
            int row = srow + it * 32;
            int grow = rb * 128 + row; if (grow >= R) grow = R - 1;
            bf16x8 va = *(const bf16x8*)(A + grow * EENC + s * 64 + sg * 8);
            *(bf16x8*)&lA[row * 64 + ((sg ^ (row & 7)) << 3)] = va;
            int col = row;
            bf16x8 vb = *(const bf16x8*)(BT + (cb * 128 + col) * EENC + s * 64 + sg * 8);
            *(bf16x8*)&lB[col * 64 + ((sg ^ (col & 7)) << 3)] = vb;
        }
        __syncthreads();
        #pragma unroll
        for (int ks = 0; ks < 2; ++ks) {
            int g = fg + ks * 4;
            bf16x8 af[4], bf[4];
            #pragma unroll
            for (int rt = 0; rt < 4; ++rt) {
                int row = rh * 64 + rt * 16 + frow;
                af[rt] = *(const bf16x8*)&lA[row * 64 + ((g ^ (row & 7)) << 3)];
            }
            #pragma unroll
            for (int c = 0; c < 4; ++c) {
                int col = ch * 64 + c * 16 + frow;
                bf[c] = *(const bf16x8*)&lB[col * 64 + ((g ^ (col & 7)) << 3)];
            }
            #pragma unroll
            for (int rt = 0; rt < 4; ++rt)
                #pragma unroll
                for (int c = 0; c < 4; ++c)
                    acc[rt][c] = __builtin_amdgcn_mfma_f32_16x16x32_bf16(af[rt], bf[c], acc[rt][c], 0, 0, 0);
        }
    }
    #pragma unroll
    for (int rt = 0; rt < 4; ++rt) {
        int grow0 = rb * 128 + rh * 64 + rt * 16 + quad * 4;
        #pragma unroll
        for (int c = 0; c < 4; ++c) {
            int col = cb * 128 + ch * 64 + c * 16 + frow;
            float b = bias ? bias[col] : 0.f;
            #pragma unroll
            for (int r = 0; r < 4; ++r) {
                int gr = grow0 + r;
                if (gr < R) C[gr * NHID + col] = acc[rt][c][r] + b;
            }
        }
    }
}

// ---- joint: per block 2 nt x 64 u(padded) x 128 vocab; fused tanh + GEMM + LSE ----
__global__ __launch_bounds__(256) void joint_mfma(
    const float* __restrict__ encp,          // [2400][512]
    const float* __restrict__ decp,          // [488][512] (b_joint folded)
    const unsigned short* __restrict__ WoT,  // [128][512] bf16
    const float* __restrict__ bo,            // [128]
    const int* __restrict__ targets,         // [8][60]
    float* __restrict__ blankp, float* __restrict__ emitp)
{
    __shared__ short lA[128 * 64];
    __shared__ short lB[128 * 64];
    __shared__ float bo_s[VOC];
    __shared__ int   lab_s[U_];
    __shared__ float red_m[2][128];
    __shared__ float red_s[2][128];

    const int tid = threadIdx.x, lane = tid & 63, wave = tid >> 6;
    const int nt0 = 2 * blockIdx.x, n = nt0 / T_;
    if (tid < VOC) bo_s[tid] = bo[tid];
    if (tid >= 128 && tid < 128 + U_) lab_s[tid - 128] = targets[n * U_ + (tid - 128)];

    const int rh = wave & 1, ch = wave >> 1;
    const int srow = (tid >> 3) & 31, sg = tid & 7;
    const int frow = lane & 15, fg = lane >> 4, quad = lane >> 4;

    f32x4 acc[4][4];
    f32x4 z = {0.f, 0.f, 0.f, 0.f};
    #pragma unroll
    for (int a = 0; a < 4; ++a)
        #pragma unroll
        for (int b = 0; b < 4; ++b) acc[a][b] = z;

    for (int s = 0; s < 8; ++s) {            // K=512, slices of 64
        __syncthreads();
        #pragma unroll
        for (int it = 0; it < 4; ++it) {
            int row = srow + it * 32;
            int u = row & 63; if (u > U_) u = U_;
            int nt = nt0 + (row >> 6);
            const float* ep = encp + nt * NHID + s * 64 + sg * 8;
            const float* dp = decp + (n * U1_ + u) * NHID + s * 64 + sg * 8;
            float4 e0 = *(const float4*)ep, e1 = *(const float4*)(ep + 4);
            float4 d0 = *(const float4*)dp, d1 = *(const float4*)(dp + 4);
            bf16x8 va;
            va[0] = (short)f2bf(fast_tanh(e0.x + d0.x));
            va[1] = (short)f2bf(fast_tanh(e0.y + d0.y));
            va[2] = (short)f2bf(fast_tanh(e0.z + d0.z));
            va[3] = (short)f2bf(fast_tanh(e0.w + d0.w));
            va[4] = (short)f2bf(fast_tanh(e1.x + d1.x));
            va[5] = (short)f2bf(fast_tanh(e1.y + d1.y));
            va[6] = (short)f2bf(fast_tanh(e1.z + d1.z));
            va[7] = (short)f2bf(fast_tanh(e1.w + d1.w));
            *(bf16x8*)&lA[row * 64 + ((sg ^ (row & 7)) << 3)] = va;
            int col = row;
            bf16x8 vb = *(const bf16x8*)(WoT + col * NHID + s * 64 + sg * 8);
            *(bf16x8*)&lB[col * 64 + ((sg ^ (col & 7)) << 3)] = vb;
        }
        __syncthreads();
        #pragma unroll
        for (int ks = 0; ks < 2; ++ks) {
            int g = fg + ks * 4;
            bf16x8 af[4], bf[4];
            #pragma unroll
            for (int rt = 0; rt < 4; ++rt) {
                int row = rh * 64 + rt * 16 + frow;
                af[rt] = *(const bf16x8*)&lA[row * 64 + ((g ^ (row & 7)) << 3)];
            }
            #pragma unroll
            for (int c = 0; c < 4; ++c) {
                int col = ch * 64 + c * 16 + frow;
                bf[c] = *(const bf16x8*)&lB[col * 64 + ((g ^ (col & 7)) << 3)];
            }
            #pragma unroll
            for (int rt = 0; rt < 4; ++rt)
                #pragma unroll
                for (int c = 0; c < 4; ++c)
                    acc[rt][c] = __builtin_amdgcn_mfma_f32_16x16x32_bf16(af[rt], bf[c], acc[rt][c], 0, 0, 0);
        }
    }

    // ---- epilogue: bias, per-row LSE over 128 cols, store blank/target ----
    #pragma unroll
    for (int rt = 0; rt < 4; ++rt)
        #pragma unroll
        for (int c = 0; c < 4; ++c) {
            float b = bo_s[ch * 64 + c * 16 + frow];
            #pragma unroll
            for (int r = 0; r < 4; ++r) acc[rt][c][r] += b;
        }

    float m_l[4][4], s_l[4][4];
    #pragma unroll
    for (int rt = 0; rt < 4; ++rt)
        #pragma unroll
        for (int r = 0; r < 4; ++r) {
            float m = -1e30f;
            #pragma unroll
            for (int c = 0; c < 4; ++c) m = fmaxf(m, acc[rt][c][r]);
            m_l[rt][r] = m;
        }
    #pragma unroll
    for (int off = 1; off < 16; off <<= 1)
        #pragma unroll
        for (int rt = 0; rt < 4; ++rt)
            #pragma unroll
            for (int r = 0; r < 4; ++r)
                m_l[rt][r] = fmaxf(m_l[rt][r], __shfl_xor(m_l[rt][r], off));
    #pragma unroll
    for (int rt = 0; rt < 4; ++rt)
        #pragma unroll
        for (int r = 0; r < 4; ++r) {
            float s = 0.f;
            #pragma unroll
            for (int c = 0; c < 4; ++c) s += __expf(acc[rt][c][r] - m_l[rt][r]);
            s_l[rt][r] = s;
        }
    #pragma unroll
    for (int off = 1; off < 16; off <<= 1)
        #pragma unroll
        for (int rt = 0; rt < 4; ++rt)
            #pragma unroll
            for (int r = 0; r < 4; ++r)
                s_l[rt][r] += __shfl_xor(s_l[rt][r], off);

    if (frow == 0) {
        #pragma unroll
        for (int rt = 0; rt < 4; ++rt)
            #pragma unroll
            for (int r = 0; r < 4; ++r) {
                int row = rh * 64 + rt * 16 + quad * 4 + r;
                red_m[ch][row] = m_l[rt][r];
                red_s[ch][row] = s_l[rt][r];
            }
    }
    __syncthreads();

    #pragma unroll
    for (int rt = 0; rt < 4; ++rt)
        #pragma unroll
        for (int r = 0; r < 4; ++r) {
            int row = rh * 64 + rt * 16 + quad * 4 + r;
            float m0 = red_m[0][row], m1 = red_m[1][row];
            float s0 = red_s[0][row], s1 = red_s[1][row];
            float M = fmaxf(m0, m1);
            float lse = M + __logf(s0 * __expf(m0 - M) + s1 * __expf(m1 - M));
            int u = row & 63;
            int nt = nt0 + (row >> 6);
            #pragma unroll
            for (int c = 0; c < 4; ++c) {
                int col = ch * 64 + c * 16 + frow;
                float val = acc[rt][c][r] - lse;
                if (col == 0 && u < U1_) blankp[nt * U1_ + u] = val;
                if (u < U_ && col == lab_s[u]) emitp[nt * U_ + u] = val;
            }
        }
}

// ---- anti-diagonal DP: 1 block per batch, LDS ring staging, wave 0 computes ----
#define RING 128
#define SBS  62   // sB row stride (2-way bank aliasing = free)
#define SES  62   // sE row stride (2-way)
__global__ __launch_bounds__(256) void dp_kernel(
    const float* __restrict__ blankp, const float* __restrict__ emitp,
    const int* __restrict__ inputs_len, const int* __restrict__ targets_len,
    float* __restrict__ out)
{
    __shared__ float sB[RING * SBS];
    __shared__ float sE[RING * SES];
    __shared__ float loss_s;

    const int n   = blockIdx.x;
    const int tid = threadIdx.x;
    const int u   = tid & 63;
    const int rg  = tid >> 6;            // 0..3 staging row group
    const float* B = blankp + n * T_ * U1_;
    const float* E = emitp  + n * T_ * U_;
    const int ti = inputs_len[n] - 1;
    const int ui = targets_len[n];

    float a = (u == 0) ? 0.f : -1e30f;
    const int uB = min(u, U_);                    // clamped LDS columns for lanes 61..63
    const int uE = min(max(u - 1, 0), U_ - 1);
    int staged = 0;

    for (int d0 = 1; d0 <= 360; d0 += 64) {
        // ---- stage rows [staged, top] of B and E into the ring ----
        int top = min(d0 + 63, T_ - 1);
        for (int r = staged + rg; r <= top; r += 4) {
            int slot = r & (RING - 1);
            if (u < U1_) sB[slot * SBS + u] = B[r * U1_ + u];
            if (u < U_)  sE[slot * SES + u] = E[r * U_  + u];
        }
        if (top >= staged) staged = top + 1;
        __syncthreads();

        if (tid < 64) {
            // depth-2 LDS read pipeline: addresses depend only on (d,u)
            #define LDB(d) sB[((unsigned)(min(max((d) - u - 1, 0), T_ - 1)) & (RING-1)) * SBS + uB]
            #define LDE(d) sE[((unsigned)(min(max((d) - u,     0), T_ - 1)) & (RING-1)) * SES + uE]
            float b0 = LDB(d0),     e0 = LDE(d0);
            float b1 = LDB(d0 + 1), e1 = LDE(d0 + 1);
            #pragma unroll 4
            for (int j = 0; j < 64; j += 2) {
                {   // step j
                    int d = d0 + j, t = d - u;
                    float b_ = b0, e_ = e0;
                    b0 = LDB(d + 2); e0 = LDE(d + 2);
                    float av = __shfl_up(a, 1);
                    if (t >= 0 && t < T_ && u < U1_) {
                        float anew;
                        if (t == 0)      anew = av + e_;
                        else if (u == 0) anew = a + b_;
                        else {
                            float x = a + b_, y = av + e_;
                            float mx = fmaxf(x, y), mn = fminf(x, y);
                            anew = mx + __logf(1.f + __expf(mn - mx));
                        }
                        a = anew;
                        if (t == ti && u == ui)
                            loss_s = -(anew + sB[((unsigned)t & (RING-1)) * SBS + u]);
                    }
                }
                {   // step j+1
                    int d = d0 + j + 1, t = d - u;
                    float b_ = b1, e_ = e1;
                    b1 = LDB(d + 2); e1 = LDE(d + 2);
                    float av = __shfl_up(a, 1);
                    if (t >= 0 && t < T_ && u < U1_) {
                        float anew;
                        if (t == 0)      anew = av + e_;
                        else if (u == 0) anew = a + b_;
                        else {
                            float x = a + b_, y = av + e_;
                            float mx = fmaxf(x, y), mn = fminf(x, y);
                            anew = mx + __logf(1.f + __expf(mn - mx));
                        }
                        a = anew;
                        if (t == ti && u == ui)
                            loss_s = -(anew + sB[((unsigned)t & (RING-1)) * SBS + u]);
                    }
                }
            }
            #undef LDB
            #undef LDE
        }
        __syncthreads();
    }
    if (tid == 0) atomicAdd(out, loss_s * (1.0f / N_));
}

extern "C" void kernel_launch(void* const* d_in, const int* in_sizes, int n_in,
                              void* d_out, int out_size, void* d_ws, size_t ws_size,
                              hipStream_t stream)
{
    const float* enc         = (const float*)d_in[0];
    const float* dec         = (const float*)d_in[1];
    const int*   targets     = (const int*)d_in[2];
    const int*   inputs_len  = (const int*)d_in[3];
    const int*   targets_len = (const int*)d_in[4];
    const float* Wj          = (const float*)d_in[5];
    const float* bj          = (const float*)d_in[6];
    const float* Wo          = (const float*)d_in[7];
    const float* bo          = (const float*)d_in[8];
    float* out = (float*)d_out;

    char* ws = (char*)d_ws;
    float*          encp   = (float*)(ws + 0);                      // 2400*512 f32
    float*          decp   = (float*)(ws + 4915200);                // 488*512 f32
    float*          blankp = (float*)(ws + 5914624);                // 8*300*61 f32
    float*          emitp  = (float*)(ws + 6500224);                // 8*300*60 f32
    unsigned short* encB   = (unsigned short*)(ws + 7076224);       // 2400*320 bf16
    unsigned short* decB   = (unsigned short*)(ws + 8612224);       // 488*320 bf16
    unsigned short* WjT    = (unsigned short*)(ws + 8924544);       // 512*320 bf16
    unsigned short* WoT    = (unsigned short*)(ws + 9252224);       // 128*512 bf16

    convert_all<<<903 + 896, 256, 0, stream>>>(enc, dec, Wj, Wo, encB, decB, WjT, WoT);
    proj_mfma<<<19 * 4, 256, 0, stream>>>(encB, WjT, nullptr, encp, N_ * T_);
    proj_mfma<<<4 * 4, 256, 0, stream>>>(decB, WjT, bj, decp, N_ * U1_);
    joint_mfma<<<1200, 256, 0, stream>>>(encp, decp, WoT, bo, targets, blankp, emitp);
    hipMemsetAsync(d_out, 0, sizeof(float), stream);
    dp_kernel<<<N_, 256, 0, stream>>>(blankp, emitp, inputs_len, targets_len, out);
}

// Round 4
// 262.764 us; speedup vs baseline: 3.2255x; 1.2460x over previous
//
#include <hip/hip_runtime.h>
#include <hip/hip_bf16.h>

#define N_   8
#define T_   300
#define U_   60
#define U1_  61
#define EENC 320
#define NHID 512
#define VOC  128

typedef __attribute__((ext_vector_type(8))) short bf16x8;
typedef __attribute__((ext_vector_type(4))) float f32x4;

__device__ __forceinline__ unsigned short f2bf(float f) {
    unsigned int u = __float_as_uint(f);
    u += 0x7fff + ((u >> 16) & 1);          // RNE
    return (unsigned short)(u >> 16);
}

// no clamp needed: e=inf -> rcp(inf)=0 -> 1; e=0 -> 1-2=-1
__device__ __forceinline__ float fast_tanh(float x) {
    float e = __expf(2.f * x);
    return 1.f - __fdividef(2.f, e + 1.f);
}

// ---- coalesced LDS-tiled transpose-convert: Wj[320,512]->WjT[512][320], Wo[512,128]->WoT[128][512] ----
__global__ __launch_bounds__(256) void convert_w(
    const float* __restrict__ Wj, const float* __restrict__ Wo,
    unsigned short* __restrict__ WjT, unsigned short* __restrict__ WoT)
{
    __shared__ float tile[32][33];
    int bid = blockIdx.x;
    const float* S; unsigned short* D; int k0, c0, K, C;
    if (bid < 160) { S = Wj; D = WjT; K = 320; C = 512; k0 = (bid >> 4) * 32; c0 = (bid & 15) * 32; }
    else { bid -= 160; S = Wo; D = WoT; K = 512; C = 128; k0 = (bid >> 2) * 32; c0 = (bid & 3) * 32; }
    const int tx = threadIdx.x & 31, ty = threadIdx.x >> 5;   // ty 0..7
    #pragma unroll
    for (int i = 0; i < 32; i += 8)
        tile[ty + i][tx] = S[(k0 + ty + i) * C + c0 + tx];
    __syncthreads();
    #pragma unroll
    for (int i = 0; i < 32; i += 8)
        D[(c0 + ty + i) * K + k0 + tx] = f2bf(tile[tx][ty + i]);
}

// ---- projection GEMM: C[R,512] = X[R,320](fp32, converted inline) @ WjT^T ----
// one launch: blocks 0..75 -> enc, 76..91 -> dec
__global__ __launch_bounds__(256) void proj_mfma(
    const float* __restrict__ Xe, const float* __restrict__ Xd,
    const unsigned short* __restrict__ BT,  // [512][320] bf16
    const float* __restrict__ bj,           // dec bias
    float* __restrict__ Ce, float* __restrict__ Cd)
{
    __shared__ short lA[128 * 64];
    __shared__ short lB[128 * 64];
    int bid = blockIdx.x;
    const float* X; float* Cp; const float* bias; int R;
    if (bid < 76) { X = Xe; Cp = Ce; bias = nullptr; R = N_ * T_; }
    else { bid -= 76; X = Xd; Cp = Cd; bias = bj; R = N_ * U1_; }
    const int tid = threadIdx.x, lane = tid & 63, wave = tid >> 6;
    const int rb = bid >> 2, cb = bid & 3;
    const int rh = wave & 1, ch = wave >> 1;
    const int srow = (tid >> 3) & 31, sg = tid & 7;
    const int frow = lane & 15, fg = lane >> 4, quad = lane >> 4;

    f32x4 acc[4][4];
    f32x4 z = {0.f, 0.f, 0.f, 0.f};
    #pragma unroll
    for (int a = 0; a < 4; ++a)
        #pragma unroll
        for (int b = 0; b < 4; ++b) acc[a][b] = z;

    for (int s = 0; s < 5; ++s) {            // K=320, slices of 64
        __syncthreads();
        #pragma unroll
        for (int it = 0; it < 4; ++it) {
            int row = srow + it * 32;
            int grow = rb * 128 + row; if (grow >= R) grow = R - 1;
            const float* xp = X + grow * EENC + s * 64 + sg * 8;
            float4 x0 = *(const float4*)xp, x1 = *(const float4*)(xp + 4);
            bf16x8 va;
            va[0] = (short)f2bf(x0.x); va[1] = (short)f2bf(x0.y);
            va[2] = (short)f2bf(x0.z); va[3] = (short)f2bf(x0.w);
            va[4] = (short)f2bf(x1.x); va[5] = (short)f2bf(x1.y);
            va[6] = (short)f2bf(x1.z); va[7] = (short)f2bf(x1.w);
            *(bf16x8*)&lA[row * 64 + ((sg ^ (row & 7)) << 3)] = va;
            int col = row;
            bf16x8 vb = *(const bf16x8*)(BT + (cb * 128 + col) * EENC + s * 64 + sg * 8);
            *(bf16x8*)&lB[col * 64 + ((sg ^ (col & 7)) << 3)] = vb;
        }
        __syncthreads();
        #pragma unroll
        for (int ks = 0; ks < 2; ++ks) {
            int g = fg + ks * 4;
            bf16x8 af[4], bf[4];
            #pragma unroll
            for (int rt = 0; rt < 4; ++rt) {
                int row = rh * 64 + rt * 16 + frow;
                af[rt] = *(const bf16x8*)&lA[row * 64 + ((g ^ (row & 7)) << 3)];
            }
            #pragma unroll
            for (int c = 0; c < 4; ++c) {
                int col = ch * 64 + c * 16 + frow;
                bf[c] = *(const bf16x8*)&lB[col * 64 + ((g ^ (col & 7)) << 3)];
            }
            #pragma unroll
            for (int rt = 0; rt < 4; ++rt)
                #pragma unroll
                for (int c = 0; c < 4; ++c)
                    acc[rt][c] = __builtin_amdgcn_mfma_f32_16x16x32_bf16(af[rt], bf[c], acc[rt][c], 0, 0, 0);
        }
    }
    #pragma unroll
    for (int rt = 0; rt < 4; ++rt) {
        int grow0 = rb * 128 + rh * 64 + rt * 16 + quad * 4;
        #pragma unroll
        for (int c = 0; c < 4; ++c) {
            int col = cb * 128 + ch * 64 + c * 16 + frow;
            float b = bias ? bias[col] : 0.f;
            #pragma unroll
            for (int r = 0; r < 4; ++r) {
                int gr = grow0 + r;
                if (gr < R) Cp[gr * NHID + col] = acc[rt][c][r] + b;
            }
        }
    }
}

// ---- joint: one block per nt; tile 64 u-rows x 128 vocab; wave-local LSE ----
__global__ __launch_bounds__(256, 5) void joint_mfma(
    const float* __restrict__ encp,          // [2400][512]
    const float* __restrict__ decp,          // [488][512] (b_joint folded)
    const unsigned short* __restrict__ WoT,  // [128][512] bf16
    const float* __restrict__ bo,            // [128]
    const int* __restrict__ targets,         // [8][60]
    float* __restrict__ blankp, float* __restrict__ emitp)
{
    __shared__ short lA[64 * 64];            // 8 KB
    __shared__ short lB[128 * 64];           // 16 KB
    __shared__ float bo_s[VOC];
    __shared__ int   lab_s[U_];

    const int tid = threadIdx.x, lane = tid & 63, wave = tid >> 6;
    const int nt = blockIdx.x, n = nt / T_;
    if (tid < VOC) bo_s[tid] = bo[tid];
    else if (tid < VOC + U_) lab_s[tid - VOC] = targets[n * U_ + (tid - VOC)];

    const int sg = tid & 7, sr = tid >> 3;   // sr 0..31
    const int frow = lane & 15, fg = lane >> 4, quad = lane >> 4;

    f32x4 acc[8];
    f32x4 z = {0.f, 0.f, 0.f, 0.f};
    #pragma unroll
    for (int c = 0; c < 8; ++c) acc[c] = z;

    const float* ep_base = encp + nt * NHID;
    for (int s = 0; s < 8; ++s) {            // K=512, slices of 64
        __syncthreads();
        // enc slice for this thread's k-chunk (row-independent, hoisted)
        const float* ep = ep_base + s * 64 + sg * 8;
        float4 e0 = *(const float4*)ep, e1 = *(const float4*)(ep + 4);
        // ---- A staging: 64 rows in 2 passes ----
        #pragma unroll
        for (int p = 0; p < 2; ++p) {
            int row = sr + p * 32;
            int u = min(row, U_);
            const float* dp = decp + (n * U1_ + u) * NHID + s * 64 + sg * 8;
            float4 d0 = *(const float4*)dp, d1 = *(const float4*)(dp + 4);
            bf16x8 va;
            va[0] = (short)f2bf(fast_tanh(e0.x + d0.x));
            va[1] = (short)f2bf(fast_tanh(e0.y + d0.y));
            va[2] = (short)f2bf(fast_tanh(e0.z + d0.z));
            va[3] = (short)f2bf(fast_tanh(e0.w + d0.w));
            va[4] = (short)f2bf(fast_tanh(e1.x + d1.x));
            va[5] = (short)f2bf(fast_tanh(e1.y + d1.y));
            va[6] = (short)f2bf(fast_tanh(e1.z + d1.z));
            va[7] = (short)f2bf(fast_tanh(e1.w + d1.w));
            *(bf16x8*)&lA[row * 64 + ((sg ^ (row & 7)) << 3)] = va;
        }
        // ---- B staging: 128 cols in 4 passes ----
        #pragma unroll
        for (int p = 0; p < 4; ++p) {
            int col = sr + p * 32;
            bf16x8 vb = *(const bf16x8*)(WoT + col * NHID + s * 64 + sg * 8);
            *(bf16x8*)&lB[col * 64 + ((sg ^ (col & 7)) << 3)] = vb;
        }
        __syncthreads();
        // ---- MFMA: each wave = 16 rows x 128 cols ----
        #pragma unroll
        for (int ks = 0; ks < 2; ++ks) {
            int g = fg + ks * 4;
            int arow = wave * 16 + frow;
            bf16x8 af = *(const bf16x8*)&lA[arow * 64 + ((g ^ (arow & 7)) << 3)];
            #pragma unroll
            for (int c = 0; c < 8; ++c) {
                int col = c * 16 + frow;
                bf16x8 bfr = *(const bf16x8*)&lB[col * 64 + ((g ^ (col & 7)) << 3)];
                acc[c] = __builtin_amdgcn_mfma_f32_16x16x32_bf16(af, bfr, acc[c], 0, 0, 0);
            }
        }
    }

    // ---- epilogue: bias + wave-local per-row LSE over 128 cols ----
    #pragma unroll
    for (int c = 0; c < 8; ++c) {
        float b = bo_s[c * 16 + frow];
        #pragma unroll
        for (int r = 0; r < 4; ++r) acc[c][r] += b;
    }
    float mx[4], sm[4];
    #pragma unroll
    for (int r = 0; r < 4; ++r) {
        float m = acc[0][r];
        #pragma unroll
        for (int c = 1; c < 8; ++c) m = fmaxf(m, acc[c][r]);
        mx[r] = m;
    }
    #pragma unroll
    for (int off = 1; off < 16; off <<= 1)
        #pragma unroll
        for (int r = 0; r < 4; ++r) mx[r] = fmaxf(mx[r], __shfl_xor(mx[r], off));
    #pragma unroll
    for (int r = 0; r < 4; ++r) {
        float s = 0.f;
        #pragma unroll
        for (int c = 0; c < 8; ++c) s += __expf(acc[c][r] - mx[r]);
        sm[r] = s;
    }
    #pragma unroll
    for (int off = 1; off < 16; off <<= 1)
        #pragma unroll
        for (int r = 0; r < 4; ++r) sm[r] += __shfl_xor(sm[r], off);

    #pragma unroll
    for (int r = 0; r < 4; ++r) {
        float lse = mx[r] + __logf(sm[r]);
        int urow = wave * 16 + quad * 4 + r;
        if (urow < U1_ && frow == 0)
            blankp[nt * U1_ + urow] = acc[0][r] - lse;
        if (urow < U_) {
            int lab = lab_s[urow];
            if (frow == (lab & 15)) {
                int cw = lab >> 4;
                float pick = acc[0][r];
                #pragma unroll
                for (int c = 1; c < 8; ++c) if (c == cw) pick = acc[c][r];
                emitp[nt * U_ + urow] = pick - lse;
            }
        }
    }
}

// ---- anti-diagonal DP: 1 block per batch, LDS ring staging, wave 0 computes ----
#define RING 128
#define SBS  62
#define SES  62
__global__ __launch_bounds__(256) void dp_kernel(
    const float* __restrict__ blankp, const float* __restrict__ emitp,
    const int* __restrict__ inputs_len, const int* __restrict__ targets_len,
    float* __restrict__ out)
{
    __shared__ float sB[RING * SBS];
    __shared__ float sE[RING * SES];
    __shared__ float loss_s;

    const int n   = blockIdx.x;
    const int tid = threadIdx.x;
    const int u   = tid & 63;
    const int rg  = tid >> 6;
    const float* B = blankp + n * T_ * U1_;
    const float* E = emitp  + n * T_ * U_;
    const int ti = inputs_len[n] - 1;
    const int ui = targets_len[n];

    float a = (u == 0) ? 0.f : -1e30f;
    const int uB = min(u, U_);
    const int uE = min(max(u - 1, 0), U_ - 1);
    int staged = 0;

    for (int d0 = 1; d0 <= 360; d0 += 64) {
        int top = min(d0 + 63, T_ - 1);
        for (int r = staged + rg; r <= top; r += 4) {
            int slot = r & (RING - 1);
            if (u < U1_) sB[slot * SBS + u] = B[r * U1_ + u];
            if (u < U_)  sE[slot * SES + u] = E[r * U_  + u];
        }
        if (top >= staged) staged = top + 1;
        __syncthreads();

        if (tid < 64) {
            #define LDB(d) sB[((unsigned)(min(max((d) - u - 1, 0), T_ - 1)) & (RING-1)) * SBS + uB]
            #define LDE(d) sE[((unsigned)(min(max((d) - u,     0), T_ - 1)) & (RING-1)) * SES + uE]
            float b0 = LDB(d0),     e0 = LDE(d0);
            float b1 = LDB(d0 + 1), e1 = LDE(d0 + 1);
            #pragma unroll 4
            for (int j = 0; j < 64; j += 2) {
                {
                    int d = d0 + j, t = d - u;
                    float b_ = b0, e_ = e0;
                    b0 = LDB(d + 2); e0 = LDE(d + 2);
                    float av = __shfl_up(a, 1);
                    if (t >= 0 && t < T_ && u < U1_) {
                        float anew;
                        if (t == 0)      anew = av + e_;
                        else if (u == 0) anew = a + b_;
                        else {
                            float x = a + b_, y = av + e_;
                            float m = fmaxf(x, y), mn = fminf(x, y);
                            anew = m + __logf(1.f + __expf(mn - m));
                        }
                        a = anew;
                        if (t == ti && u == ui)
                            loss_s = -(anew + sB[((unsigned)t & (RING-1)) * SBS + u]);
                    }
                }
                {
                    int d = d0 + j + 1, t = d - u;
                    float b_ = b1, e_ = e1;
                    b1 = LDB(d + 2); e1 = LDE(d + 2);
                    float av = __shfl_up(a, 1);
                    if (t >= 0 && t < T_ && u < U1_) {
                        float anew;
                        if (t == 0)      anew = av + e_;
                        else if (u == 0) anew = a + b_;
                        else {
                            float x = a + b_, y = av + e_;
                            float m = fmaxf(x, y), mn = fminf(x, y);
                            anew = m + __logf(1.f + __expf(mn - m));
                        }
                        a = anew;
                        if (t == ti && u == ui)
                            loss_s = -(anew + sB[((unsigned)t & (RING-1)) * SBS + u]);
                    }
                }
            }
            #undef LDB
            #undef LDE
        }
        __syncthreads();
    }
    if (tid == 0) atomicAdd(out, loss_s * (1.0f / N_));
}

extern "C" void kernel_launch(void* const* d_in, const int* in_sizes, int n_in,
                              void* d_out, int out_size, void* d_ws, size_t ws_size,
                              hipStream_t stream)
{
    const float* enc         = (const float*)d_in[0];
    const float* dec         = (const float*)d_in[1];
    const int*   targets     = (const int*)d_in[2];
    const int*   inputs_len  = (const int*)d_in[3];
    const int*   targets_len = (const int*)d_in[4];
    const float* Wj          = (const float*)d_in[5];
    const float* bj          = (const float*)d_in[6];
    const float* Wo          = (const float*)d_in[7];
    const float* bo          = (const float*)d_in[8];
    float* out = (float*)d_out;

    char* ws = (char*)d_ws;
    float*          encp   = (float*)(ws + 0);                // 2400*512 f32 = 4,915,200
    float*          decp   = (float*)(ws + 4915200);          // 488*512 f32  =   999,424
    float*          blankp = (float*)(ws + 5914624);          // 8*300*61 f32 =   585,600
    float*          emitp  = (float*)(ws + 6500224);          // 8*300*60 f32 =   576,000
    unsigned short* WjT    = (unsigned short*)(ws + 7076224); // 512*320 bf16 =   327,680
    unsigned short* WoT    = (unsigned short*)(ws + 7403904); // 128*512 bf16 =   131,072

    convert_w<<<224, 256, 0, stream>>>(Wj, Wo, WjT, WoT);
    proj_mfma<<<92, 256, 0, stream>>>(enc, dec, WjT, bj, encp, decp);
    joint_mfma<<<N_ * T_, 256, 0, stream>>>(encp, decp, WoT, bo, targets, blankp, emitp);
    hipMemsetAsync(d_out, 0, sizeof(float), stream);
    dp_kernel<<<N_, 256, 0, stream>>>(blankp, emitp, inputs_len, targets_len, out);
}

// Round 5
// 251.989 us; speedup vs baseline: 3.3634x; 1.0428x over previous
//
#include <hip/hip_runtime.h>
#include <hip/hip_bf16.h>

#define N_   8
#define T_   300
#define U_   60
#define U1_  61
#define EENC 320
#define NHID 512
#define VOC  128
#define SKROWS 384   // padded skew-row count (t+u in [0,359], prefetch reads to 368)

typedef __attribute__((ext_vector_type(8))) short bf16x8;
typedef __attribute__((ext_vector_type(4))) float f32x4;

__device__ __forceinline__ unsigned short f2bf(float f) {
    unsigned int u = __float_as_uint(f);
    u += 0x7fff + ((u >> 16) & 1);          // RNE
    return (unsigned short)(u >> 16);
}

// no clamp needed: e=inf -> rcp(inf)=0 -> 1; e=0 -> 1-2=-1
__device__ __forceinline__ float fast_tanh(float x) {
    float e = __expf(2.f * x);
    return 1.f - __fdividef(2.f, e + 1.f);
}

// logaddexp via -|x-y| (exp input modifier folds the negate/abs)
__device__ __forceinline__ float lae(float x, float y) {
    float m = fmaxf(x, y);
    float z = __expf(-fabsf(x - y));
    return m + __logf(1.f + z);
}

// ---- coalesced LDS-tiled transpose-convert: Wj[320,512]->WjT[512][320], Wo[512,128]->WoT[128][512] ----
__global__ __launch_bounds__(256) void convert_w(
    const float* __restrict__ Wj, const float* __restrict__ Wo,
    unsigned short* __restrict__ WjT, unsigned short* __restrict__ WoT)
{
    __shared__ float tile[32][33];
    int bid = blockIdx.x;
    const float* S; unsigned short* D; int k0, c0, K, C;
    if (bid < 160) { S = Wj; D = WjT; K = 320; C = 512; k0 = (bid >> 4) * 32; c0 = (bid & 15) * 32; }
    else { bid -= 160; S = Wo; D = WoT; K = 512; C = 128; k0 = (bid >> 2) * 32; c0 = (bid & 3) * 32; }
    const int tx = threadIdx.x & 31, ty = threadIdx.x >> 5;   // ty 0..7
    #pragma unroll
    for (int i = 0; i < 32; i += 8)
        tile[ty + i][tx] = S[(k0 + ty + i) * C + c0 + tx];
    __syncthreads();
    #pragma unroll
    for (int i = 0; i < 32; i += 8)
        D[(c0 + ty + i) * K + k0 + tx] = f2bf(tile[tx][ty + i]);
}

// ---- projection GEMM: C[R,512] = X[R,320](fp32, converted inline) @ WjT^T ----
// one launch: blocks 0..75 -> enc, 76..91 -> dec
__global__ __launch_bounds__(256) void proj_mfma(
    const float* __restrict__ Xe, const float* __restrict__ Xd,
    const unsigned short* __restrict__ BT,  // [512][320] bf16
    const float* __restrict__ bj,           // dec bias
    float* __restrict__ Ce, float* __restrict__ Cd)
{
    __shared__ short lA[128 * 64];
    __shared__ short lB[128 * 64];
    int bid = blockIdx.x;
    const float* X; float* Cp; const float* bias; int R;
    if (bid < 76) { X = Xe; Cp = Ce; bias = nullptr; R = N_ * T_; }
    else { bid -= 76; X = Xd; Cp = Cd; bias = bj; R = N_ * U1_; }
    const int tid = threadIdx.x, lane = tid & 63, wave = tid >> 6;
    const int rb = bid >> 2, cb = bid & 3;
    const int rh = wave & 1, ch = wave >> 1;
    const int srow = (tid >> 3) & 31, sg = tid & 7;
    const int frow = lane & 15, fg = lane >> 4, quad = lane >> 4;

    f32x4 acc[4][4];
    f32x4 z = {0.f, 0.f, 0.f, 0.f};
    #pragma unroll
    for (int a = 0; a < 4; ++a)
        #pragma unroll
        for (int b = 0; b < 4; ++b) acc[a][b] = z;

    for (int s = 0; s < 5; ++s) {            // K=320, slices of 64
        __syncthreads();
        #pragma unroll
        for (int it = 0; it < 4; ++it) {
            int row = srow + it * 32;
            int grow = rb * 128 + row; if (grow >= R) grow = R - 1;
            const float* xp = X + grow * EENC + s * 64 + sg * 8;
            float4 x0 = *(const float4*)xp, x1 = *(const float4*)(xp + 4);
            bf16x8 va;
            va[0] = (short)f2bf(x0.x); va[1] = (short)f2bf(x0.y);
            va[2] = (short)f2bf(x0.z); va[3] = (short)f2bf(x0.w);
            va[4] = (short)f2bf(x1.x); va[5] = (short)f2bf(x1.y);
            va[6] = (short)f2bf(x1.z); va[7] = (short)f2bf(x1.w);
            *(bf16x8*)&lA[row * 64 + ((sg ^ (row & 7)) << 3)] = va;
            int col = row;
            bf16x8 vb = *(const bf16x8*)(BT + (cb * 128 + col) * EENC + s * 64 + sg * 8);
            *(bf16x8*)&lB[col * 64 + ((sg ^ (col & 7)) << 3)] = vb;
        }
        __syncthreads();
        #pragma unroll
        for (int ks = 0; ks < 2; ++ks) {
            int g = fg + ks * 4;
            bf16x8 af[4], bf[4];
            #pragma unroll
            for (int rt = 0; rt < 4; ++rt) {
                int row = rh * 64 + rt * 16 + frow;
                af[rt] = *(const bf16x8*)&lA[row * 64 + ((g ^ (row & 7)) << 3)];
            }
            #pragma unroll
            for (int c = 0; c < 4; ++c) {
                int col = ch * 64 + c * 16 + frow;
                bf[c] = *(const bf16x8*)&lB[col * 64 + ((g ^ (col & 7)) << 3)];
            }
            #pragma unroll
            for (int rt = 0; rt < 4; ++rt)
                #pragma unroll
                for (int c = 0; c < 4; ++c)
                    acc[rt][c] = __builtin_amdgcn_mfma_f32_16x16x32_bf16(af[rt], bf[c], acc[rt][c], 0, 0, 0);
        }
    }
    #pragma unroll
    for (int rt = 0; rt < 4; ++rt) {
        int grow0 = rb * 128 + rh * 64 + rt * 16 + quad * 4;
        #pragma unroll
        for (int c = 0; c < 4; ++c) {
            int col = cb * 128 + ch * 64 + c * 16 + frow;
            float b = bias ? bias[col] : 0.f;
            #pragma unroll
            for (int r = 0; r < 4; ++r) {
                int gr = grow0 + r;
                if (gr < R) Cp[gr * NHID + col] = acc[rt][c][r] + b;
            }
        }
    }
}

// ---- joint: one block per nt; tile 64 u-rows x 128 vocab; wave-local LSE ----
// Outputs in SKEWED layout: skewB[n][t+u][u] = blank_lp, skewE[n][t+u+1][u+1] = emit_lp
__global__ __launch_bounds__(256, 5) void joint_mfma(
    const float* __restrict__ encp,          // [2400][512]
    const float* __restrict__ decp,          // [488][512] (b_joint folded)
    const unsigned short* __restrict__ WoT,  // [128][512] bf16
    const float* __restrict__ bo,            // [128]
    const int* __restrict__ targets,         // [8][60]
    float* __restrict__ skewB, float* __restrict__ skewE)
{
    __shared__ short lA[64 * 64];            // 8 KB
    __shared__ short lB[128 * 64];           // 16 KB
    __shared__ float bo_s[VOC];
    __shared__ int   lab_s[U_];

    const int tid = threadIdx.x, lane = tid & 63, wave = tid >> 6;
    const int nt = blockIdx.x, n = nt / T_;
    const int t = nt - n * T_;
    if (tid < VOC) bo_s[tid] = bo[tid];
    else if (tid < VOC + U_) lab_s[tid - VOC] = targets[n * U_ + (tid - VOC)];

    const int sg = tid & 7, sr = tid >> 3;   // sr 0..31
    const int frow = lane & 15, fg = lane >> 4, quad = lane >> 4;

    f32x4 acc[8];
    f32x4 z = {0.f, 0.f, 0.f, 0.f};
    #pragma unroll
    for (int c = 0; c < 8; ++c) acc[c] = z;

    const float* ep_base = encp + nt * NHID;
    for (int s = 0; s < 8; ++s) {            // K=512, slices of 64
        __syncthreads();
        const float* ep = ep_base + s * 64 + sg * 8;
        float4 e0 = *(const float4*)ep, e1 = *(const float4*)(ep + 4);
        #pragma unroll
        for (int p = 0; p < 2; ++p) {
            int row = sr + p * 32;
            int u = min(row, U_);
            const float* dp = decp + (n * U1_ + u) * NHID + s * 64 + sg * 8;
            float4 d0 = *(const float4*)dp, d1 = *(const float4*)(dp + 4);
            bf16x8 va;
            va[0] = (short)f2bf(fast_tanh(e0.x + d0.x));
            va[1] = (short)f2bf(fast_tanh(e0.y + d0.y));
            va[2] = (short)f2bf(fast_tanh(e0.z + d0.z));
            va[3] = (short)f2bf(fast_tanh(e0.w + d0.w));
            va[4] = (short)f2bf(fast_tanh(e1.x + d1.x));
            va[5] = (short)f2bf(fast_tanh(e1.y + d1.y));
            va[6] = (short)f2bf(fast_tanh(e1.z + d1.z));
            va[7] = (short)f2bf(fast_tanh(e1.w + d1.w));
            *(bf16x8*)&lA[row * 64 + ((sg ^ (row & 7)) << 3)] = va;
        }
        #pragma unroll
        for (int p = 0; p < 4; ++p) {
            int col = sr + p * 32;
            bf16x8 vb = *(const bf16x8*)(WoT + col * NHID + s * 64 + sg * 8);
            *(bf16x8*)&lB[col * 64 + ((sg ^ (col & 7)) << 3)] = vb;
        }
        __syncthreads();
        #pragma unroll
        for (int ks = 0; ks < 2; ++ks) {
            int g = fg + ks * 4;
            int arow = wave * 16 + frow;
            bf16x8 af = *(const bf16x8*)&lA[arow * 64 + ((g ^ (arow & 7)) << 3)];
            #pragma unroll
            for (int c = 0; c < 8; ++c) {
                int col = c * 16 + frow;
                bf16x8 bfr = *(const bf16x8*)&lB[col * 64 + ((g ^ (col & 7)) << 3)];
                acc[c] = __builtin_amdgcn_mfma_f32_16x16x32_bf16(af, bfr, acc[c], 0, 0, 0);
            }
        }
    }

    // ---- epilogue: bias + wave-local per-row LSE over 128 cols ----
    #pragma unroll
    for (int c = 0; c < 8; ++c) {
        float b = bo_s[c * 16 + frow];
        #pragma unroll
        for (int r = 0; r < 4; ++r) acc[c][r] += b;
    }
    float mx[4], sm[4];
    #pragma unroll
    for (int r = 0; r < 4; ++r) {
        float m = acc[0][r];
        #pragma unroll
        for (int c = 1; c < 8; ++c) m = fmaxf(m, acc[c][r]);
        mx[r] = m;
    }
    #pragma unroll
    for (int off = 1; off < 16; off <<= 1)
        #pragma unroll
        for (int r = 0; r < 4; ++r) mx[r] = fmaxf(mx[r], __shfl_xor(mx[r], off));
    #pragma unroll
    for (int r = 0; r < 4; ++r) {
        float s = 0.f;
        #pragma unroll
        for (int c = 0; c < 8; ++c) s += __expf(acc[c][r] - mx[r]);
        sm[r] = s;
    }
    #pragma unroll
    for (int off = 1; off < 16; off <<= 1)
        #pragma unroll
        for (int r = 0; r < 4; ++r) sm[r] += __shfl_xor(sm[r], off);

    #pragma unroll
    for (int r = 0; r < 4; ++r) {
        float lse = mx[r] + __logf(sm[r]);
        int urow = wave * 16 + quad * 4 + r;
        if (urow < U1_ && frow == 0)
            skewB[((size_t)n * SKROWS + t + urow) * 64 + urow] = acc[0][r] - lse;
        if (urow < U_) {
            int lab = lab_s[urow];
            if (frow == (lab & 15)) {
                int cw = lab >> 4;
                float pick = acc[0][r];
                #pragma unroll
                for (int c = 1; c < 8; ++c) if (c == cw) pick = acc[c][r];
                skewE[((size_t)n * SKROWS + t + urow + 1) * 64 + urow + 1] = pick - lse;
            }
        }
    }
}

// ---- anti-diagonal DP, g=4 cells/lane, skewed float4 operands, vmcnt prefetch ----
// 2 blocks x 64 threads; block b handles batches 4b..4b+3 (16 lanes each).
__global__ __launch_bounds__(64) void dp_kernel(
    const float* __restrict__ skewB, const float* __restrict__ skewE,
    const int* __restrict__ inputs_len, const int* __restrict__ targets_len,
    float* __restrict__ out)
{
    const int lane = threadIdx.x;            // 0..63
    const int n    = blockIdx.x * 4 + (lane >> 4);
    const int c    = lane & 15;
    const int u0   = c * 4;                  // lane owns u = u0..u0+3
    const float* B = skewB + (size_t)n * SKROWS * 64;
    const float* E = skewE + (size_t)n * SKROWS * 64;
    const unsigned len_t = (unsigned)inputs_len[n];   // valid t in [0, len_t)
    const int ui = targets_len[n];
    const int ti = (int)len_t - 1;
    const bool u_is0 = (c == 0);

    float a0 = u_is0 ? 0.f : -1e30f;         // alpha(0,0)=0 initial
    float a1 = -1e30f, a2 = -1e30f, a3 = -1e30f;

    // 8-diagonal register prefetch pipeline (vmcnt-decoupled from shfl's lgkm)
    float4 blq[8], emq[8];
    #pragma unroll
    for (int j = 0; j < 8; ++j) {
        int d = 1 + j;
        blq[j] = *(const float4*)(B + (d - 1) * 64 + u0);
        emq[j] = *(const float4*)(E + d * 64 + u0);
    }

    for (int d0 = 1; d0 < 361; d0 += 8) {
        #pragma unroll
        for (int j = 0; j < 8; ++j) {
            const int d = d0 + j;
            float4 bl = blq[j], em = emq[j];
            blq[j] = *(const float4*)(B + (d + 7) * 64 + u0);   // row (d+8)-1
            emq[j] = *(const float4*)(E + (d + 8) * 64 + u0);
            float av0 = __shfl_up(a3, 1);    // neighbor lane's old a3 (u0-1)
            float em0 = u_is0 ? -1e30f : em.x;
            // all four cells read only OLD values (prev diagonal)
            float n0 = lae(a0 + bl.x, av0 + em0);
            float n1 = lae(a1 + bl.y, a0 + em.y);
            float n2 = lae(a2 + bl.z, a1 + em.z);
            float n3 = lae(a3 + bl.w, a2 + em.w);
            // commit where t = d-u is in range (unsigned trick covers t<0)
            a0 = ((unsigned)(d - u0)     < len_t) ? n0 : a0;
            a1 = ((unsigned)(d - u0 - 1) < len_t) ? n1 : a1;
            a2 = ((unsigned)(d - u0 - 2) < len_t) ? n2 : a2;
            a3 = ((unsigned)(d - u0 - 3) < len_t) ? n3 : a3;
        }
    }

    float av[4] = {a0, a1, a2, a3};
    #pragma unroll
    for (int j = 0; j < 4; ++j)
        if (u0 + j == ui) {
            float bfin = B[(ti + ui) * 64 + ui];
            atomicAdd(out, -(av[j] + bfin) * (1.0f / N_));
        }
}

extern "C" void kernel_launch(void* const* d_in, const int* in_sizes, int n_in,
                              void* d_out, int out_size, void* d_ws, size_t ws_size,
                              hipStream_t stream)
{
    const float* enc         = (const float*)d_in[0];
    const float* dec         = (const float*)d_in[1];
    const int*   targets     = (const int*)d_in[2];
    const int*   inputs_len  = (const int*)d_in[3];
    const int*   targets_len = (const int*)d_in[4];
    const float* Wj          = (const float*)d_in[5];
    const float* bj          = (const float*)d_in[6];
    const float* Wo          = (const float*)d_in[7];
    const float* bo          = (const float*)d_in[8];
    float* out = (float*)d_out;

    char* ws = (char*)d_ws;
    float*          encp  = (float*)(ws + 0);                // 2400*512 f32 = 4,915,200
    float*          decp  = (float*)(ws + 4915200);          // 488*512 f32  =   999,424
    float*          skewB = (float*)(ws + 5914624);          // 8*384*64 f32 =   786,432
    float*          skewE = (float*)(ws + 6701056);          // 8*384*64 f32 =   786,432
    unsigned short* WjT   = (unsigned short*)(ws + 7487488); // 512*320 bf16 =   327,680
    unsigned short* WoT   = (unsigned short*)(ws + 7815168); // 128*512 bf16 =   131,072

    convert_w<<<224, 256, 0, stream>>>(Wj, Wo, WjT, WoT);
    proj_mfma<<<92, 256, 0, stream>>>(enc, dec, WjT, bj, encp, decp);
    joint_mfma<<<N_ * T_, 256, 0, stream>>>(encp, decp, WoT, bo, targets, skewB, skewE);
    hipMemsetAsync(d_out, 0, sizeof(float), stream);
    dp_kernel<<<2, 64, 0, stream>>>(skewB, skewE, inputs_len, targets_len, out);
}

// Round 6
// 227.863 us; speedup vs baseline: 3.7196x; 1.1059x over previous
//
#include <hip/hip_runtime.h>
#include <hip/hip_bf16.h>
#include <hip/hip_fp16.h>

#define N_   8
#define T_   300
#define U_   60
#define U1_  61
#define EENC 320
#define NHID 512
#define VOC  128
#define SKROWS 384
#define INV_LN2 1.4426950408889634f
#define LN2 0.6931471805599453f

typedef __attribute__((ext_vector_type(8))) short bf16x8;
typedef __attribute__((ext_vector_type(4))) float f32x4;

__device__ __forceinline__ unsigned short f2bf(float f) {
    unsigned int u = __float_as_uint(f);
    u += 0x7fff + ((u >> 16) & 1);          // RNE
    return (unsigned short)(u >> 16);
}

__device__ __forceinline__ float fast_tanh(float x) {
    float e = __expf(2.f * x);
    return 1.f - __fdividef(2.f, e + 1.f);
}

// log-add-exp in log2 domain: returns log2(2^x + 2^y)
__device__ __forceinline__ float lae2(float x, float y) {
    float m = fmaxf(x, y);
    return m + log2f(1.f + exp2f(-fabsf(x - y)));
}

// compiler-proof async 16B load (pipeline kept in registers, drained by explicit vmcnt)
__device__ __forceinline__ float4 gload16(const void* p) {
    float4 v;
    asm volatile("global_load_dwordx4 %0, %1, off" : "=v"(v) : "v"(p) : "memory");
    return v;
}
#define WAITVM(n) __builtin_amdgcn_s_waitcnt(0x0F70 | (n))

// ---- coalesced LDS-tiled transpose-convert: Wj[320,512]->WjT[512][320], Wo[512,128]->WoT[128][512] ----
__global__ __launch_bounds__(256) void convert_w(
    const float* __restrict__ Wj, const float* __restrict__ Wo,
    unsigned short* __restrict__ WjT, unsigned short* __restrict__ WoT)
{
    __shared__ float tile[32][33];
    int bid = blockIdx.x;
    const float* S; unsigned short* D; int k0, c0, K, C;
    if (bid < 160) { S = Wj; D = WjT; K = 320; C = 512; k0 = (bid >> 4) * 32; c0 = (bid & 15) * 32; }
    else { bid -= 160; S = Wo; D = WoT; K = 512; C = 128; k0 = (bid >> 2) * 32; c0 = (bid & 3) * 32; }
    const int tx = threadIdx.x & 31, ty = threadIdx.x >> 5;
    #pragma unroll
    for (int i = 0; i < 32; i += 8)
        tile[ty + i][tx] = S[(k0 + ty + i) * C + c0 + tx];
    __syncthreads();
    #pragma unroll
    for (int i = 0; i < 32; i += 8)
        D[(c0 + ty + i) * K + k0 + tx] = f2bf(tile[tx][ty + i]);
}

// ---- projection GEMM: C[R,512] = X[R,320](fp32, converted inline) @ WjT^T ----
__global__ __launch_bounds__(256) void proj_mfma(
    const float* __restrict__ Xe, const float* __restrict__ Xd,
    const unsigned short* __restrict__ BT,
    const float* __restrict__ bj,
    float* __restrict__ Ce, float* __restrict__ Cd)
{
    __shared__ short lA[128 * 64];
    __shared__ short lB[128 * 64];
    int bid = blockIdx.x;
    const float* X; float* Cp; const float* bias; int R;
    if (bid < 76) { X = Xe; Cp = Ce; bias = nullptr; R = N_ * T_; }
    else { bid -= 76; X = Xd; Cp = Cd; bias = bj; R = N_ * U1_; }
    const int tid = threadIdx.x, lane = tid & 63, wave = tid >> 6;
    const int rb = bid >> 2, cb = bid & 3;
    const int rh = wave & 1, ch = wave >> 1;
    const int srow = (tid >> 3) & 31, sg = tid & 7;
    const int frow = lane & 15, fg = lane >> 4, quad = lane >> 4;

    f32x4 acc[4][4];
    f32x4 z = {0.f, 0.f, 0.f, 0.f};
    #pragma unroll
    for (int a = 0; a < 4; ++a)
        #pragma unroll
        for (int b = 0; b < 4; ++b) acc[a][b] = z;

    for (int s = 0; s < 5; ++s) {
        __syncthreads();
        #pragma unroll
        for (int it = 0; it < 4; ++it) {
            int row = srow + it * 32;
            int grow = rb * 128 + row; if (grow >= R) grow = R - 1;
            const float* xp = X + grow * EENC + s * 64 + sg * 8;
            float4 x0 = *(const float4*)xp, x1 = *(const float4*)(xp + 4);
            bf16x8 va;
            va[0] = (short)f2bf(x0.x); va[1] = (short)f2bf(x0.y);
            va[2] = (short)f2bf(x0.z); va[3] = (short)f2bf(x0.w);
            va[4] = (short)f2bf(x1.x); va[5] = (short)f2bf(x1.y);
            va[6] = (short)f2bf(x1.z); va[7] = (short)f2bf(x1.w);
            *(bf16x8*)&lA[row * 64 + ((sg ^ (row & 7)) << 3)] = va;
            int col = row;
            bf16x8 vb = *(const bf16x8*)(BT + (cb * 128 + col) * EENC + s * 64 + sg * 8);
            *(bf16x8*)&lB[col * 64 + ((sg ^ (col & 7)) << 3)] = vb;
        }
        __syncthreads();
        #pragma unroll
        for (int ks = 0; ks < 2; ++ks) {
            int g = fg + ks * 4;
            bf16x8 af[4], bf[4];
            #pragma unroll
            for (int rt = 0; rt < 4; ++rt) {
                int row = rh * 64 + rt * 16 + frow;
                af[rt] = *(const bf16x8*)&lA[row * 64 + ((g ^ (row & 7)) << 3)];
            }
            #pragma unroll
            for (int c = 0; c < 4; ++c) {
                int col = ch * 64 + c * 16 + frow;
                bf[c] = *(const bf16x8*)&lB[col * 64 + ((g ^ (col & 7)) << 3)];
            }
            #pragma unroll
            for (int rt = 0; rt < 4; ++rt)
                #pragma unroll
                for (int c = 0; c < 4; ++c)
                    acc[rt][c] = __builtin_amdgcn_mfma_f32_16x16x32_bf16(af[rt], bf[c], acc[rt][c], 0, 0, 0);
        }
    }
    #pragma unroll
    for (int rt = 0; rt < 4; ++rt) {
        int grow0 = rb * 128 + rh * 64 + rt * 16 + quad * 4;
        #pragma unroll
        for (int c = 0; c < 4; ++c) {
            int col = cb * 128 + ch * 64 + c * 16 + frow;
            float b = bias ? bias[col] : 0.f;
            #pragma unroll
            for (int r = 0; r < 4; ++r) {
                int gr = grow0 + r;
                if (gr < R) Cp[gr * NHID + col] = acc[rt][c][r] + b;
            }
        }
    }
}

// ---- joint: one block per nt; 64 u-rows x 128 vocab; wave-local LSE ----
// Output: packed fp16 skew array Z[n][row][u] = half2{bl, em}, values pre-scaled by 1/ln2.
//   bl(t,u)  -> Z[t+u+1][u].x ; em(t,ur) -> Z[t+ur+1][ur+1].y
__global__ __launch_bounds__(256, 5) void joint_mfma(
    const float* __restrict__ encp,
    const float* __restrict__ decp,
    const unsigned short* __restrict__ WoT,
    const float* __restrict__ bo,
    const int* __restrict__ targets,
    unsigned short* __restrict__ Zs)      // half-bits view of Z
{
    __shared__ short lA[64 * 64];
    __shared__ short lB[128 * 64];
    __shared__ float bo_s[VOC];
    __shared__ int   lab_s[U_];

    const int tid = threadIdx.x, lane = tid & 63, wave = tid >> 6;
    const int nt = blockIdx.x, n = nt / T_;
    const int t = nt - n * T_;
    if (tid < VOC) bo_s[tid] = bo[tid];
    else if (tid < VOC + U_) lab_s[tid - VOC] = targets[n * U_ + (tid - VOC)];

    const int sg = tid & 7, sr = tid >> 3;
    const int frow = lane & 15, fg = lane >> 4, quad = lane >> 4;

    f32x4 acc[8];
    f32x4 z = {0.f, 0.f, 0.f, 0.f};
    #pragma unroll
    for (int c = 0; c < 8; ++c) acc[c] = z;

    const float* ep_base = encp + nt * NHID;
    for (int s = 0; s < 8; ++s) {
        __syncthreads();
        const float* ep = ep_base + s * 64 + sg * 8;
        float4 e0 = *(const float4*)ep, e1 = *(const float4*)(ep + 4);
        #pragma unroll
        for (int p = 0; p < 2; ++p) {
            int row = sr + p * 32;
            int u = min(row, U_);
            const float* dp = decp + (n * U1_ + u) * NHID + s * 64 + sg * 8;
            float4 d0 = *(const float4*)dp, d1 = *(const float4*)(dp + 4);
            bf16x8 va;
            va[0] = (short)f2bf(fast_tanh(e0.x + d0.x));
            va[1] = (short)f2bf(fast_tanh(e0.y + d0.y));
            va[2] = (short)f2bf(fast_tanh(e0.z + d0.z));
            va[3] = (short)f2bf(fast_tanh(e0.w + d0.w));
            va[4] = (short)f2bf(fast_tanh(e1.x + d1.x));
            va[5] = (short)f2bf(fast_tanh(e1.y + d1.y));
            va[6] = (short)f2bf(fast_tanh(e1.z + d1.z));
            va[7] = (short)f2bf(fast_tanh(e1.w + d1.w));
            *(bf16x8*)&lA[row * 64 + ((sg ^ (row & 7)) << 3)] = va;
        }
        #pragma unroll
        for (int p = 0; p < 4; ++p) {
            int col = sr + p * 32;
            bf16x8 vb = *(const bf16x8*)(WoT + col * NHID + s * 64 + sg * 8);
            *(bf16x8*)&lB[col * 64 + ((sg ^ (col & 7)) << 3)] = vb;
        }
        __syncthreads();
        #pragma unroll
        for (int ks = 0; ks < 2; ++ks) {
            int g = fg + ks * 4;
            int arow = wave * 16 + frow;
            bf16x8 af = *(const bf16x8*)&lA[arow * 64 + ((g ^ (arow & 7)) << 3)];
            #pragma unroll
            for (int c = 0; c < 8; ++c) {
                int col = c * 16 + frow;
                bf16x8 bfr = *(const bf16x8*)&lB[col * 64 + ((g ^ (col & 7)) << 3)];
                acc[c] = __builtin_amdgcn_mfma_f32_16x16x32_bf16(af, bfr, acc[c], 0, 0, 0);
            }
        }
    }

    #pragma unroll
    for (int c = 0; c < 8; ++c) {
        float b = bo_s[c * 16 + frow];
        #pragma unroll
        for (int r = 0; r < 4; ++r) acc[c][r] += b;
    }
    float mx[4], sm[4];
    #pragma unroll
    for (int r = 0; r < 4; ++r) {
        float m = acc[0][r];
        #pragma unroll
        for (int c = 1; c < 8; ++c) m = fmaxf(m, acc[c][r]);
        mx[r] = m;
    }
    #pragma unroll
    for (int off = 1; off < 16; off <<= 1)
        #pragma unroll
        for (int r = 0; r < 4; ++r) mx[r] = fmaxf(mx[r], __shfl_xor(mx[r], off));
    #pragma unroll
    for (int r = 0; r < 4; ++r) {
        float s = 0.f;
        #pragma unroll
        for (int c = 0; c < 8; ++c) s += __expf(acc[c][r] - mx[r]);
        sm[r] = s;
    }
    #pragma unroll
    for (int off = 1; off < 16; off <<= 1)
        #pragma unroll
        for (int r = 0; r < 4; ++r) sm[r] += __shfl_xor(sm[r], off);

    #pragma unroll
    for (int r = 0; r < 4; ++r) {
        float lse = mx[r] + __logf(sm[r]);
        int urow = wave * 16 + quad * 4 + r;
        size_t rowz = (size_t)(n * SKROWS + t + urow + 1) * 64;
        if (urow < U1_ && frow == 0) {
            __half h = __float2half_rn((acc[0][r] - lse) * INV_LN2);
            Zs[(rowz + urow) * 2] = __half_as_ushort(h);
        }
        if (urow < U_) {
            int lab = lab_s[urow];
            if (frow == (lab & 15)) {
                int cw = lab >> 4;
                float pick = acc[0][r];
                #pragma unroll
                for (int c = 1; c < 8; ++c) if (c == cw) pick = acc[c][r];
                __half h = __float2half_rn((pick - lse) * INV_LN2);
                Zs[(rowz + urow + 1) * 2 + 1] = __half_as_ushort(h);
            }
        }
    }
}

// ---- anti-diagonal DP: 2 blocks x 256. Wave 0 computes (4 batches x 16 lanes, 4 u/lane);
//      waves 1-3 stream the block's Z region to warm L2. asm-pinned 8-deep vmcnt pipeline. ----
__global__ __launch_bounds__(256) void dp_kernel(
    const unsigned* __restrict__ Z,      // half2-as-uint [N][SKROWS][64]
    const int* __restrict__ inputs_len, const int* __restrict__ targets_len,
    float* __restrict__ out, float* __restrict__ scrap)
{
    const int tid = threadIdx.x;
    const int nb0 = blockIdx.x * 4;
    if (tid >= 64) {                     // L2 warmers
        const float4* W = (const float4*)(Z + (size_t)nb0 * SKROWS * 64);
        float acc = 0.f;
        const int nv = 4 * SKROWS * 64 / 4;
        for (int i = tid - 64; i < nv; i += 192) acc += W[i].x;
        if (__float_as_uint(acc) == 0x7F123456u) scrap[0] = acc;   // DCE guard, never true in practice
        return;
    }
    const int lane = tid;
    const int n  = nb0 + (lane >> 4);
    const int c  = lane & 15;
    const int u0 = c * 4;
    const char* Zn = (const char*)(Z + (size_t)n * SKROWS * 64) + u0 * 4;
    const unsigned len_t = (unsigned)inputs_len[n];
    const int ui = targets_len[n];
    const int ti = (int)len_t - 1;
    const bool u_is0 = (c == 0);

    float a0 = u_is0 ? 0.f : -1e30f;
    float a1 = -1e30f, a2 = -1e30f, a3 = -1e30f;

    float4 zq[8];
    #pragma unroll
    for (int j = 0; j < 8; ++j) zq[j] = gload16(Zn + (size_t)(1 + j) * 256);

    for (int d0 = 1; d0 < 361; d0 += 8) {
        #pragma unroll
        for (int j = 0; j < 8; ++j) {
            const int d = d0 + j;
            WAITVM(7);                               // retire slot j's load (oldest)
            float4 zv = zq[j];
            zq[j] = gload16(Zn + (size_t)(d + 8) * 256);
            const __half2* hz = (const __half2*)&zv;
            float2 w0 = __half22float2(hz[0]);
            float2 w1 = __half22float2(hz[1]);
            float2 w2 = __half22float2(hz[2]);
            float2 w3 = __half22float2(hz[3]);
            float av0 = __shfl_up(a3, 1);
            float e0 = u_is0 ? -1e30f : w0.y;
            float n0 = lae2(a0 + w0.x, av0 + e0);
            float n1 = lae2(a1 + w1.x, a0 + w1.y);
            float n2 = lae2(a2 + w2.x, a1 + w2.y);
            float n3 = lae2(a3 + w3.x, a2 + w3.y);
            a0 = ((unsigned)(d - u0)     < len_t) ? n0 : a0;
            a1 = ((unsigned)(d - u0 - 1) < len_t) ? n1 : a1;
            a2 = ((unsigned)(d - u0 - 2) < len_t) ? n2 : a2;
            a3 = ((unsigned)(d - u0 - 3) < len_t) ? n3 : a3;
        }
    }
    WAITVM(0);
    float av[4] = {a0, a1, a2, a3};
    #pragma unroll
    for (int j = 0; j < 4; ++j)
        if (u0 + j == ui) {
            const __half2* hf = (const __half2*)((const char*)(Z + (size_t)n * SKROWS * 64)
                                                 + ((size_t)(ti + ui + 1) * 64 + ui) * 4);
            float blf = __half22float2(hf[0]).x;
            atomicAdd(out, -(av[j] + blf) * (LN2 / N_));
        }
}

extern "C" void kernel_launch(void* const* d_in, const int* in_sizes, int n_in,
                              void* d_out, int out_size, void* d_ws, size_t ws_size,
                              hipStream_t stream)
{
    const float* enc         = (const float*)d_in[0];
    const float* dec         = (const float*)d_in[1];
    const int*   targets     = (const int*)d_in[2];
    const int*   inputs_len  = (const int*)d_in[3];
    const int*   targets_len = (const int*)d_in[4];
    const float* Wj          = (const float*)d_in[5];
    const float* bj          = (const float*)d_in[6];
    const float* Wo          = (const float*)d_in[7];
    const float* bo          = (const float*)d_in[8];
    float* out = (float*)d_out;

    char* ws = (char*)d_ws;
    float*          encp  = (float*)(ws + 0);                // 2400*512 f32 = 4,915,200
    float*          decp  = (float*)(ws + 4915200);          // 488*512 f32  =   999,424
    unsigned*       Z     = (unsigned*)(ws + 5914624);       // 8*384*64 half2 = 786,432
    unsigned short* WjT   = (unsigned short*)(ws + 6701056); // 512*320 bf16 =   327,680
    unsigned short* WoT   = (unsigned short*)(ws + 7028736); // 128*512 bf16 =   131,072
    float*          scrap = (float*)(ws + 7159808);          // 64 B

    convert_w<<<224, 256, 0, stream>>>(Wj, Wo, WjT, WoT);
    proj_mfma<<<92, 256, 0, stream>>>(enc, dec, WjT, bj, encp, decp);
    joint_mfma<<<N_ * T_, 256, 0, stream>>>(encp, decp, WoT, bo, targets, (unsigned short*)Z);
    hipMemsetAsync(d_out, 0, sizeof(float), stream);
    dp_kernel<<<2, 256, 0, stream>>>(Z, inputs_len, targets_len, out, scrap);
}